// Round 5
// baseline (554.760 us; speedup 1.0000x reference)
//
#include <hip/hip_runtime.h>
#include <hip/hip_bf16.h>

#define B_ 64
#define S_ 2048
#define D_ 512   // D_ENC = D_DEC = UNITS = 512
#define ROWS 64  // enc rows per block

typedef __attribute__((ext_vector_type(8))) short bf16x8;
typedef __attribute__((ext_vector_type(4))) float f32x4;

__device__ inline short f2bf(float f) {
    __hip_bfloat16 h = __float2bfloat16(f);   // RNE
    return __builtin_bit_cast(short, h);
}
__device__ inline float bf2f(short s) {
    return __uint_as_float(((unsigned)(unsigned short)s) << 16);
}
__device__ inline float fast_tanh(float x) {
    float xc = fminf(fmaxf(x, -15.f), 15.f);
    float t = __expf(2.f * xc);
    return (t - 1.f) * __builtin_amdgcn_rcpf(t + 1.f);
}

// ---------------- hdec[b][u] = dec[b]@W2[:,u] + b1[u] + b2[u] ----------------
__global__ __launch_bounds__(128)
void hdec_kernel(const float* __restrict__ dec, const float* __restrict__ W2,
                 const float* __restrict__ b1, const float* __restrict__ b2,
                 float* __restrict__ hdec)
{
    int b = blockIdx.x >> 2;
    int u = (blockIdx.x & 3) * 128 + threadIdx.x;
    __shared__ float ds[512];
    for (int i = threadIdx.x; i < 512; i += 128) ds[i] = dec[b * 512 + i];
    __syncthreads();
    float acc = b1[u] + b2[u];
    const float* wp = W2 + u;
    #pragma unroll 8
    for (int k = 0; k < 512; ++k)
        acc = fmaf(ds[k], wp[(size_t)k * 512], acc);
    hdec[b * 512 + u] = acc;
}

// ---------------- W1T[u][d] = bf16(W1[d][u]) ----------------
__global__ void w1t_kernel(const float* __restrict__ W1, short* __restrict__ W1T)
{
    __shared__ float tile[64][65];
    int d0 = blockIdx.x * 64;
    int u0 = blockIdx.y * 64;
    int tx = threadIdx.x & 63;
    int ty = threadIdx.x >> 6;   // 0..3
    #pragma unroll
    for (int i = 0; i < 16; ++i) {
        int d = ty + i * 4;
        tile[d][tx] = W1[(size_t)(d0 + d) * 512 + u0 + tx];
    }
    __syncthreads();
    #pragma unroll
    for (int i = 0; i < 16; ++i) {
        int u = ty + i * 4;
        W1T[(size_t)(u0 + u) * 512 + d0 + tx] = f2bf(tile[tx][u]);
    }
}

// ---------------- main fused kernel ----------------
// grid 2048 = 64 b x 32 chunks of 64 rows; block 256 (4 waves).
// Wave w owns u in [w*128, w*128+128): 8 u-tiles, processed as 2 passes of NU=4.
// Software-pipelined K-loop: depth-2 prefetch for W1T (global), depth-1 for A (LDS).
__global__ __launch_bounds__(256, 2)
void attn_main(const float* __restrict__ enc, const short* __restrict__ W1T,
               const float* __restrict__ hdec, const float* __restrict__ Vv,
               float* __restrict__ partials)
{
    const int blk = blockIdx.x;
    const int b = blk >> 5;
    const int chunk = blk & 31;
    const int tid = threadIdx.x;
    const int w = tid >> 6;
    const int l = tid & 63;
    const int lc = l & 15;    // mfma row/col within 16x16 tile
    const int lg = l >> 4;    // k-group

    __shared__ short enc_s[ROWS * 512];   // 64 KB, byte ^ ((row&7)<<4) swizzle
    __shared__ float s_sc[4][64];
    __shared__ float s_p[64];
    __shared__ float s_ml[2];

    const float* encB = enc + ((size_t)b * S_ + chunk * ROWS) * D_;

    // ---- P1: stage enc tile -> LDS bf16 (swizzled). Coalesced 32B/thread/iter. ----
    #pragma unroll
    for (int i = 0; i < 16; ++i) {
        int e = i * 2048 + tid * 8;            // elem index in [64][512]
        f32x4 p0 = *(const f32x4*)(encB + e);
        f32x4 p1 = *(const f32x4*)(encB + e + 4);
        bf16x8 v;
        v[0] = f2bf(p0[0]); v[1] = f2bf(p0[1]); v[2] = f2bf(p0[2]); v[3] = f2bf(p0[3]);
        v[4] = f2bf(p1[0]); v[5] = f2bf(p1[1]); v[6] = f2bf(p1[2]); v[7] = f2bf(p1[3]);
        int row = e >> 9;
        int byte = (e * 2) ^ ((row & 7) << 4);
        *(bf16x8*)((char*)enc_s + byte) = v;
    }
    __syncthreads();

    // ---- P2: score GEMM, software-pipelined ----
    float sacc[4][4];   // [g][r] partial over this wave's u-range; row = g*16+lg*4+r
    #pragma unroll
    for (int g = 0; g < 4; ++g)
        #pragma unroll
        for (int r = 0; r < 4; ++r) sacc[g][r] = 0.f;

    const char* encs_c = (const char*)enc_s;
    const int swz = (lc & 7) << 4;

    #pragma unroll
    for (int np = 0; np < 2; ++np) {
        f32x4 acc[4][4];                       // [g][nn]
        #pragma unroll
        for (int g = 0; g < 4; ++g)
            #pragma unroll
            for (int nn = 0; nn < 4; ++nn) acc[g][nn] = f32x4{0.f, 0.f, 0.f, 0.f};

        // per-wave W1T base for this np: rows (w*128 + np*64 + nn*16 + lc)
        const short* wb = W1T + (size_t)(w * 128 + np * 64 + lc) * 512 + lg * 8;

        bf16x8 a_c[4], a_n[4];
        bf16x8 b0[4], b1v[4], b2v[4];

        // prologue: B for kk=0,1; A for kk=0
        #pragma unroll
        for (int nn = 0; nn < 4; ++nn) {
            b0[nn]  = *(const bf16x8*)(wb + (size_t)nn * 16 * 512);
            b1v[nn] = *(const bf16x8*)(wb + (size_t)nn * 16 * 512 + 32);
        }
        #pragma unroll
        for (int g = 0; g < 4; ++g) {
            int row = g * 16 + lc;
            a_c[g] = *(const bf16x8*)(encs_c + ((row * 1024 + lg * 16) ^ swz));
        }

        #pragma unroll
        for (int kk = 0; kk < 16; ++kk) {
            // prefetch A for kk+1 (LDS, depth 1)
            if (kk < 15) {
                #pragma unroll
                for (int g = 0; g < 4; ++g) {
                    int row = g * 16 + lc;
                    a_n[g] = *(const bf16x8*)(encs_c + ((row * 1024 + (kk + 1) * 64 + lg * 16) ^ swz));
                }
            }
            // prefetch B for kk+2 (global, depth 2)
            if (kk < 14) {
                #pragma unroll
                for (int nn = 0; nn < 4; ++nn)
                    b2v[nn] = *(const bf16x8*)(wb + (size_t)nn * 16 * 512 + (kk + 2) * 32);
            }
            // 16 MFMAs on current fragments
            #pragma unroll
            for (int g = 0; g < 4; ++g) {
                acc[g][0] = __builtin_amdgcn_mfma_f32_16x16x32_bf16(a_c[g], b0[0], acc[g][0], 0, 0, 0);
                acc[g][1] = __builtin_amdgcn_mfma_f32_16x16x32_bf16(a_c[g], b0[1], acc[g][1], 0, 0, 0);
                acc[g][2] = __builtin_amdgcn_mfma_f32_16x16x32_bf16(a_c[g], b0[2], acc[g][2], 0, 0, 0);
                acc[g][3] = __builtin_amdgcn_mfma_f32_16x16x32_bf16(a_c[g], b0[3], acc[g][3], 0, 0, 0);
            }
            // rotate pipeline registers (renamed away by full unroll)
            #pragma unroll
            for (int i = 0; i < 4; ++i) {
                a_c[i] = a_n[i];
                b0[i] = b1v[i];
                b1v[i] = b2v[i];
            }
        }

        // epilogue: tanh + V-dot for the 4 u-tiles of this np
        #pragma unroll
        for (int nn = 0; nn < 4; ++nn) {
            int u = (w * 8 + np * 4 + nn) * 16 + lc;
            float hd = hdec[b * 512 + u];
            float vv = Vv[u];
            #pragma unroll
            for (int g = 0; g < 4; ++g)
                #pragma unroll
                for (int r = 0; r < 4; ++r)
                    sacc[g][r] += fast_tanh(acc[g][nn][r] + hd) * vv;
        }
    }

    // ---- P3: reduce over u (16 lc lanes), cross-wave, softmax on wave 0 ----
    #pragma unroll
    for (int g = 0; g < 4; ++g) {
        #pragma unroll
        for (int r = 0; r < 4; ++r) {
            float v = sacc[g][r];
            v += __shfl_xor(v, 1);
            v += __shfl_xor(v, 2);
            v += __shfl_xor(v, 4);
            v += __shfl_xor(v, 8);
            if (lc == 0) s_sc[w][g * 16 + lg * 4 + r] = v;   // row = g*16+lg*4+r
        }
    }
    __syncthreads();
    if (w == 0) {
        float x = s_sc[0][l] + s_sc[1][l] + s_sc[2][l] + s_sc[3][l];
        float mx = x;
        #pragma unroll
        for (int o = 32; o >= 1; o >>= 1) mx = fmaxf(mx, __shfl_xor(mx, o));
        float p = __expf(x - mx);
        float ps = p;
        #pragma unroll
        for (int o = 32; o >= 1; o >>= 1) ps += __shfl_xor(ps, o);
        s_p[l] = p;
        if (l == 0) { s_ml[0] = mx; s_ml[1] = ps; }
    }
    __syncthreads();

    // ---- P4: context partial. Wave w: d-slice w*128..+127. ----
    // lane l: dblk = l&15 -> d = w*128 + dblk*8 (8 floats); rgrp = l>>4 -> rows rgrp*16..+15.
    {
        const int dblk = l & 15;
        const int rgrp = l >> 4;
        const int dbyte = w * 256 + dblk * 16;
        float c8[8] = {0.f, 0.f, 0.f, 0.f, 0.f, 0.f, 0.f, 0.f};
        #pragma unroll
        for (int rr = 0; rr < 16; ++rr) {
            int row = rgrp * 16 + rr;
            bf16x8 ev = *(const bf16x8*)(encs_c + ((row * 1024 + dbyte) ^ ((row & 7) << 4)));
            float p = s_p[row];
            #pragma unroll
            for (int j = 0; j < 8; ++j) c8[j] = fmaf(p, bf2f(ev[j]), c8[j]);
        }
        // reduce across the 4 row-groups (lanes differing in bits 4,5)
        #pragma unroll
        for (int j = 0; j < 8; ++j) {
            c8[j] += __shfl_xor(c8[j], 16);
            c8[j] += __shfl_xor(c8[j], 32);
        }
        float* part = partials + (size_t)blk * 514;
        if (rgrp == 0) {
            #pragma unroll
            for (int j = 0; j < 8; ++j)
                part[w * 128 + dblk * 8 + j] = c8[j];
        }
        if (tid == 0) { part[512] = s_ml[0]; part[513] = s_ml[1]; }
    }
}

// ---------------- merge: online-softmax merge of 32 chunks per batch ----------------
__global__ void merge_kernel(const float* __restrict__ partials, float* __restrict__ out)
{
    int b = blockIdx.x;     // 64
    int tid = threadIdx.x;  // 256
    const float* pb = partials + (size_t)b * 32 * 514;
    float M = -1e30f;
    #pragma unroll
    for (int i = 0; i < 32; ++i) M = fmaxf(M, pb[i * 514 + 512]);
    float sc[32]; float L = 0.f;
    #pragma unroll
    for (int i = 0; i < 32; ++i) {
        sc[i] = __expf(pb[i * 514 + 512] - M);
        L += pb[i * 514 + 513] * sc[i];
    }
    float inv = 1.0f / L;
    int d = tid * 2;
    #pragma unroll
    for (int t = 0; t < 2; ++t) {
        float acc = 0.f;
        #pragma unroll
        for (int i = 0; i < 32; ++i) acc += pb[i * 514 + d + t] * sc[i];
        out[b * 512 + d + t] = acc * inv;
    }
}

extern "C" void kernel_launch(void* const* d_in, const int* in_sizes, int n_in,
                              void* d_out, int out_size, void* d_ws, size_t ws_size,
                              hipStream_t stream)
{
    const float* enc = (const float*)d_in[0];
    const float* dec = (const float*)d_in[1];
    const float* W1  = (const float*)d_in[2];
    const float* b1  = (const float*)d_in[3];
    const float* W2  = (const float*)d_in[4];
    const float* b2  = (const float*)d_in[5];
    const float* V   = (const float*)d_in[6];
    // d_in[7] = bv: softmax-invariant, dropped.
    float* out = (float*)d_out;

    char* ws = (char*)d_ws;
    float* hdec     = (float*)ws;                                  // 64*512 f32   = 128 KiB
    short* W1T      = (short*)(ws + 64 * 512 * 4);                 // 512*512 bf16 = 512 KiB
    float* partials = (float*)(ws + 64 * 512 * 4 + 512 * 512 * 2); // 2048*514 f32 ~ 4.2 MiB

    hipLaunchKernelGGL(hdec_kernel, dim3(256), dim3(128), 0, stream, dec, W2, b1, b2, hdec);
    hipLaunchKernelGGL(w1t_kernel, dim3(8, 8), dim3(256), 0, stream, W1, W1T);
    hipLaunchKernelGGL(attn_main, dim3(2048), dim3(256), 0, stream, enc, W1T, hdec, V, partials);
    hipLaunchKernelGGL(merge_kernel, dim3(64), dim3(256), 0, stream, partials, out);
}